// Round 18
// baseline (1374.269 us; speedup 1.0000x reference)
//
#include <hip/hip_runtime.h>
#include <stdint.h>
#include <math.h>

// ---------------------------------------------------------------------------
// Swin block, MI355X. B=32 H=W=112 C=192 NH=6 hd=32 WS=7 SS=3 -> 8192 windows,
// 49 tokens, 401408 token-rows.
// R18 = R16 (two SEPARATED L3-blocked chunk loops — merged loop's ~250MB
// working set hit L3 capacity and regressed) + attn-only deltas isolated:
// 5 blocks/CU (LDS 32KB x 5 = 160KB) and V-fragment loads hoisted before
// QK^T (scattered u16 gathers overlap Q/K loads + MFMAs).
// ---------------------------------------------------------------------------

typedef unsigned short u16;
typedef unsigned int   u32;
typedef __bf16 v8bf __attribute__((ext_vector_type(8)));
typedef float  v4f  __attribute__((ext_vector_type(4)));
typedef u16    v8u16 __attribute__((ext_vector_type(8)));
typedef u16    v4u16 __attribute__((ext_vector_type(4)));

#define MFMA16(a,b,c) __builtin_amdgcn_mfma_f32_16x16x32_bf16(a,b,c,0,0,0)

#define QSC  0.17677669529663687f

__device__ __forceinline__ u16 f2bf(float f){
  return __builtin_bit_cast(u16, (__bf16)f);   // v_cvt RNE
}

__device__ __forceinline__ void async16(void* lds, const void* g){
  __builtin_amdgcn_global_load_lds(
      (__attribute__((address_space(1))) void*)(g),
      (__attribute__((address_space(3))) void*)(lds), 16, 0, 0);
}

// --------------------- combined weight convert (contiguous dst) ------------
// q-rows of qkv_w (first 192*192 elems) pre-scaled by hd^-0.5.
__global__ __launch_bounds__(256)
void convw(const float* __restrict__ s0, const float* __restrict__ s1,
           const float* __restrict__ s2, const float* __restrict__ s3,
           u16* __restrict__ d){
  int i = blockIdx.x * 256 + threadIdx.x;        // < 442368
  float v;
  if (i < 110592){
    v = s0[i];
    if (i < 36864) v *= QSC;
  }
  else if (i < 147456)  v = s1[i - 110592];
  else if (i < 294912)  v = s2[i - 147456];
  else                  v = s3[i - 294912];
  d[i] = f2bf(v);
}

// -------------------- fused rel-pos-bias + shift-mask table ----------------
// layout: [cls][h][m][n][lr][lg*4+r]  (matches MFMA C fragment, b128/lane)
__global__ __launch_bounds__(256)
void bmt_k(const float* __restrict__ rpb, float* __restrict__ bmt){
  int idx = blockIdx.x * 256 + threadIdx.x;      // 98304 total
  int r  = idx & 3, lg = (idx >> 2) & 3, lr = (idx >> 4) & 15;
  int n  = (idx >> 8) & 3, m = (idx >> 10) & 3;
  int t  = idx >> 12; int h = t % 6, cls = t / 6;
  int row = m*16 + lg*4 + r, col = n*16 + lr;
  float v;
  if (row >= 49 || col >= 49){
    v = -1e30f;
  } else {
    int i1 = row / 7, j1 = row - i1 * 7;
    int i2 = col / 7, j2 = col - i2 * 7;
    int ridx = (i1 - i2 + 6) * 13 + (j1 - j2 + 6);
    v = rpb[ridx * 6 + h];
    int lh1 = (cls & 2) ? (i1 < 4 ? 1 : 2) : 0;
    int lw1 = (cls & 1) ? (j1 < 4 ? 1 : 2) : 0;
    int lh2 = (cls & 2) ? (i2 < 4 ? 1 : 2) : 0;
    int lw2 = (cls & 1) ? (j2 < 4 ? 1 : 2) : 0;
    if (lh1 * 3 + lw1 != lh2 * 3 + lw2) v -= 100.f;
  }
  bmt[idx] = v;
}

// ----------------------- LayerNorm (optionally gathered, chunked) ----------
// 16 lanes per token, 4 tokens per wave; lane handles 12 channels (3 float4).
template<bool GATHER>
__global__ __launch_bounds__(256)
void ln_kern(const float* __restrict__ x, const float* __restrict__ g,
             const float* __restrict__ b, u16* __restrict__ o, int rowOff){
  const int ts  = threadIdx.x >> 4;
  const int l16 = threadIdx.x & 15;
  const int rl  = blockIdx.x * 16 + ts;          // chunk-local row
  const int r   = rowOff + rl;                   // global row
  const float* src;
  if (GATHER){
    u32 wdx = (u32)r / 49u; int nn = r - (int)wdx * 49;
    int bb = (int)(wdx >> 8); int wl = (int)(wdx & 255);
    int wh = wl >> 4, wwi = wl & 15;
    int ii = (int)((u32)nn / 7u), jj = nn - ii * 7;
    int th = wh * 7 + ii + 3;  if (th >= 112) th -= 112;
    int tw = wwi * 7 + jj + 3; if (tw >= 112) tw -= 112;
    src = x + (u32)(bb * 12544 + th * 112 + tw) * 192u;
  } else {
    src = x + (u32)r * 192u;
  }
  const float4 a0 = *(const float4*)(src + l16*12);
  const float4 a1 = *(const float4*)(src + l16*12 + 4);
  const float4 a2 = *(const float4*)(src + l16*12 + 8);
  float sm = ((a0.x+a0.y)+(a0.z+a0.w)) + ((a1.x+a1.y)+(a1.z+a1.w))
           + ((a2.x+a2.y)+(a2.z+a2.w));
  float sq = ((a0.x*a0.x+a0.y*a0.y)+(a0.z*a0.z+a0.w*a0.w))
           + ((a1.x*a1.x+a1.y*a1.y)+(a1.z*a1.z+a1.w*a1.w))
           + ((a2.x*a2.x+a2.y*a2.y)+(a2.z*a2.z+a2.w*a2.w));
  #pragma unroll
  for (int d = 1; d < 16; d <<= 1){
    sm += __shfl_xor(sm, d, 64);
    sq += __shfl_xor(sq, d, 64);
  }
  float mean = sm * (1.f/192.f);
  float var  = sq * (1.f/192.f) - mean * mean;
  float rs   = rsqrtf(var + 1e-5f);
  const float4 g0 = *(const float4*)(g + l16*12);
  const float4 g1 = *(const float4*)(g + l16*12 + 4);
  const float4 g2 = *(const float4*)(g + l16*12 + 8);
  const float4 b0 = *(const float4*)(b + l16*12);
  const float4 b1 = *(const float4*)(b + l16*12 + 4);
  const float4 b2 = *(const float4*)(b + l16*12 + 8);
  u16* dst = o + (u32)rl * 192u + l16 * 12;
  v4u16 w0, w1, w2;
  w0[0]=f2bf((a0.x-mean)*rs*g0.x+b0.x); w0[1]=f2bf((a0.y-mean)*rs*g0.y+b0.y);
  w0[2]=f2bf((a0.z-mean)*rs*g0.z+b0.z); w0[3]=f2bf((a0.w-mean)*rs*g0.w+b0.w);
  w1[0]=f2bf((a1.x-mean)*rs*g1.x+b1.x); w1[1]=f2bf((a1.y-mean)*rs*g1.y+b1.y);
  w1[2]=f2bf((a1.z-mean)*rs*g1.z+b1.z); w1[3]=f2bf((a1.w-mean)*rs*g1.w+b1.w);
  w2[0]=f2bf((a2.x-mean)*rs*g2.x+b2.x); w2[1]=f2bf((a2.y-mean)*rs*g2.y+b2.y);
  w2[2]=f2bf((a2.z-mean)*rs*g2.z+b2.z); w2[3]=f2bf((a2.w-mean)*rs*g2.w+b2.w);
  *(v4u16*)(dst)     = w0;
  *(v4u16*)(dst + 4) = w1;
  *(v4u16*)(dst + 8) = w2;
}

// ------------------------------- GEMM (A @ W^T) ----------------------------
// BM=128, BN=64, BK=192/stage, 512 threads = 8 waves, wave = 32x32 quadrant.
// 1D grid, XCD-aligned group swizzle (56 row-blocks x ncol, col-major).
// TRN = (EPI==0): acc[n][m] = mfma(wf, af) -> D[channel][token], packed 8B
// stores (chunk-local qkv, stride hstr). Else acc[m][n] -> D[token][channel].
// EPI: 0 qkv chunk store | 1 proj scatter+residual (global row = oRowOff+..)
//      2 fc1 gelu (chunk-local) | 3 fc2 linear += at global oRowOff
template<int EPI, int LDA, int LDW>
__global__ __launch_bounds__(512)
void gemm_bt(const u16* __restrict__ A, int aRowOff,
             const u16* __restrict__ W, int K, int ncol,
             const float* __restrict__ bias,
             u16* __restrict__ ob, float* __restrict__ of,
             const float* __restrict__ xres, int oRowOff, u32 hstr){
  constexpr bool TRN = (EPI == 0);
  __shared__ __align__(16) u16 sA[128 * 200];
  __shared__ __align__(16) u16 sW[64 * 200];
  const int tid = threadIdx.x;
  const int wv = tid >> 6, lnn = tid & 63;
  const int lr = lnn & 15, lg = lnn >> 4;
  // group swizzle
  const int win = 56 * ncol;
  const int grp = (int)blockIdx.x / win, loc = (int)blockIdx.x - grp * win;
  const int rloc = loc % 56, cblk = loc / 56;
  const int m0   = (grp * 56 + rloc) * 128;
  const int col0 = cblk * 64;
  const int wr = wv >> 1, wc = wv & 1;

  const int c0   = col0 + wc*32 + lr;        // untransposed: channel per lane
  const int chb0 = col0 + wc*32 + lg*4;      // transposed: 4-channel base
  const int chb1 = chb0 + 16;

  v4f acc[2][2];     // TRN: [n][m] channel-major; else [m][n] token-major
  if (TRN){
    float4 bv0 = *(const float4*)&bias[chb0];
    float4 bv1 = *(const float4*)&bias[chb1];
    if (chb0 < 192){ bv0.x*=QSC; bv0.y*=QSC; bv0.z*=QSC; bv0.w*=QSC; }
    if (chb1 < 192){ bv1.x*=QSC; bv1.y*=QSC; bv1.z*=QSC; bv1.w*=QSC; }
    acc[0][0] = acc[0][1] = (v4f){bv0.x, bv0.y, bv0.z, bv0.w};
    acc[1][0] = acc[1][1] = (v4f){bv1.x, bv1.y, bv1.z, bv1.w};
  } else {
    const float b0v = bias[c0];
    const float b1v = bias[c0 + 16];
    #pragma unroll
    for (int m = 0; m < 2; ++m){
      acc[m][0] = (v4f){b0v, b0v, b0v, b0v};
      acc[m][1] = (v4f){b1v, b1v, b1v, b1v};
    }
  }

  const int rA0 = (int)((u32)tid / 25u);
  const int cA0 = tid - rA0 * 25;
  const u32 aBase = (u32)(aRowOff + m0);
  const int nK = K / 192;
  for (int ks = 0; ks < nK; ++ks){
    if (ks) __syncthreads();
    const int k0 = ks * 192;
    // A tile: 128 rows x 25 chunks(16B) = 3200; 6 iters + 128-tail
    int ra = rA0, ca = cA0;
    #pragma unroll
    for (int it = 0; it < 6; ++it){
      int cc = (ca == 24) ? 23 : ca;
      async16((char*)sA + (size_t)(it * 512 + wv * 64) * 16,
              A + (aBase + (u32)ra) * (u32)LDA + (u32)(k0 + cc * 8));
      ra += 20; ca += 12; if (ca >= 25){ ca -= 25; ra += 1; }
    }
    if (tid < 128){
      int cc = (ca == 24) ? 23 : ca;
      async16((char*)sA + (size_t)(3072 + wv * 64) * 16,
              A + (aBase + (u32)ra) * (u32)LDA + (u32)(k0 + cc * 8));
    }
    // W tile: 64 rows x 25 chunks = 1600; 3 iters + 64-tail
    int rw = rA0, cw = cA0;
    #pragma unroll
    for (int it = 0; it < 3; ++it){
      int cc = (cw == 24) ? 23 : cw;
      async16((char*)sW + (size_t)(it * 512 + wv * 64) * 16,
              W + (u32)(col0 + rw) * (u32)LDW + (u32)(k0 + cc * 8));
      rw += 20; cw += 12; if (cw >= 25){ cw -= 25; rw += 1; }
    }
    if (tid < 64){
      int cc = (cw == 24) ? 23 : cw;
      async16((char*)sW + (size_t)1536 * 16,
              W + (u32)(col0 + rw) * (u32)LDW + (u32)(k0 + cc * 8));
    }
    __syncthreads();   // drains vmcnt(0) -> staged data visible

    #pragma unroll
    for (int kk = 0; kk < 6; ++kk){
      v8bf af[2], wf[2];
      #pragma unroll
      for (int m = 0; m < 2; ++m)
        af[m] = *(const v8bf*)&sA[(wr*32 + m*16 + lr) * 200 + kk*32 + lg*8];
      #pragma unroll
      for (int n = 0; n < 2; ++n)
        wf[n] = *(const v8bf*)&sW[(wc*32 + n*16 + lr) * 200 + kk*32 + lg*8];
      if (TRN){
        #pragma unroll
        for (int n = 0; n < 2; ++n)
          #pragma unroll
          for (int m = 0; m < 2; ++m)
            acc[n][m] = MFMA16(wf[n], af[m], acc[n][m]);
      } else {
        #pragma unroll
        for (int m = 0; m < 2; ++m)
          #pragma unroll
          for (int n = 0; n < 2; ++n)
            acc[m][n] = MFMA16(af[m], wf[n], acc[m][n]);
      }
    }
  }

  // ------------------------------ epilogues --------------------------------
  if (EPI == 0){
    // TRN: D row = channel (4*lg+r), D col = token (lr); packed 8B stores.
    u32 chpart[2];
    const int chbs[2] = {chb0, chb1};
    #pragma unroll
    for (int n = 0; n < 2; ++n){
      int ch = chbs[n];
      int which = (ch >= 384) ? 2 : ((ch >= 192) ? 1 : 0);
      int rem = ch - which * 192;
      chpart[n] = (u32)which * hstr + (u32)((rem >> 5) * 1568 + (rem & 31));
    }
    #pragma unroll
    for (int m = 0; m < 2; ++m){
      const int t = m0 + wr*32 + m*16 + lr;
      u32 wdx = (u32)t / 49u; u32 tnn = (u32)t - wdx * 49u;
      const u32 rowpart = wdx * 9408u + tnn * 32u;
      #pragma unroll
      for (int n = 0; n < 2; ++n){
        v4u16 pk;
        pk[0] = f2bf(acc[n][m][0]); pk[1] = f2bf(acc[n][m][1]);
        pk[2] = f2bf(acc[n][m][2]); pk[3] = f2bf(acc[n][m][3]);
        *(v4u16*)&ob[chpart[n] + rowpart] = pk;
      }
    }
  } else if (EPI == 1){
    // global row = oRowOff + local; window->spatial scatter + residual
    #pragma unroll
    for (int m = 0; m < 2; ++m){
      #pragma unroll
      for (int r = 0; r < 4; ++r){
        const int gr = oRowOff + m0 + wr*32 + m*16 + lg*4 + r;
        u32 wdx = (u32)gr / 49u; int nn = gr - (int)wdx * 49;
        int bb = (int)(wdx >> 8); int wl = (int)(wdx & 255);
        int wh = wl >> 4, wwi = wl & 15;
        int ii = (int)((u32)nn / 7u), jj = nn - ii * 7;
        int th = wh * 7 + ii + 3;  if (th >= 112) th -= 112;
        int tw = wwi * 7 + jj + 3; if (tw >= 112) tw -= 112;
        u32 adr = (u32)(bb * 12544 + th * 112 + tw) * 192u + (u32)c0;
        of[adr]      = xres[adr]      + acc[m][0][r];
        of[adr + 16] = xres[adr + 16] + acc[m][1][r];
      }
    }
  } else if (EPI == 3){
    // rows already spatial -> linear += at global oRowOff (lane-contiguous)
    #pragma unroll
    for (int m = 0; m < 2; ++m){
      #pragma unroll
      for (int r = 0; r < 4; ++r){
        const u32 adr = (u32)(oRowOff + m0 + wr*32 + m*16 + lg*4 + r) * 192u
                        + (u32)c0;
        of[adr]      += acc[m][0][r];
        of[adr + 16] += acc[m][1][r];
      }
    }
  } else {  // EPI == 2: gelu -> h1 chunk-local bf16, lane-contiguous
    #pragma unroll
    for (int m = 0; m < 2; ++m){
      #pragma unroll
      for (int r = 0; r < 4; ++r){
        const u32 base = (u32)(m0 + wr*32 + m*16 + lg*4 + r) * 768u + (u32)c0;
        float v0 = acc[m][0][r], v1 = acc[m][1][r];
        ob[base]      = f2bf(0.5f * v0 * (1.0f + erff(v0 * 0.7071067811865475f)));
        ob[base + 16] = f2bf(0.5f * v1 * (1.0f + erff(v1 * 0.7071067811865475f)));
      }
    }
  }
}

// ------------------------------- attention (chunk-local I/O) ---------------
// one wave per (window, head); 4 waves / block; 5 blocks/CU (LDS 32KB x 5).
// V loads issued FIRST so the scattered u16 gathers overlap Q/K + QK^T MFMAs.
__global__ __launch_bounds__(256, 5)
void attn_k(const u16* __restrict__ qkv, const float* __restrict__ bmt,
            u16* __restrict__ aout, u32 wOff, u32 hstr){
  __shared__ __align__(16) u16 plds[4][64 * 64];   // 32 KB total
  const int wv = threadIdx.x >> 6, lnn = threadIdx.x & 63;
  const int lr = lnn & 15, lg = lnn >> 4;
  const u32 gid = (u32)blockIdx.x * 4u + (u32)wv;   // chunk-local
  const u32 w = gid / 6u; const int h = (int)(gid - w * 6u);
  const u16* qb = qkv + (size_t)gid * 1568;
  const u16* kb = qb + hstr;
  const u16* vb = kb + hstr;
  const u32 wg = w + wOff;                          // global window (mask only)

  // V fragments first (k-permuted; pads multiply P==0 -> harmless)
  v8u16 bvu[2][2];
  #pragma unroll
  for (int n2 = 0; n2 < 2; ++n2)
    #pragma unroll
    for (int ksi = 0; ksi < 2; ++ksi)
      #pragma unroll
      for (int e = 0; e < 8; ++e){
        int kp = ksi * 32 + lg * 8 + e;
        int t  = (kp >> 2) + (kp & 3) * 16;
        bvu[n2][ksi][e] = vb[(u32)(t * 32 + n2 * 16 + lr)];
      }

  // C-init = bias+mask table (b128 per lane, L2/L3-resident)
  const int wl = (int)(wg & 255u);
  const int cls = (((wl >> 4) == 15) ? 2 : 0) | (((wl & 15) == 15) ? 1 : 0);
  const float* bmv = bmt + ((u32)(cls * 6 + h) << 12);
  v4f s[4][4];
  #pragma unroll
  for (int m = 0; m < 4; ++m)
    #pragma unroll
    for (int n = 0; n < 4; ++n)
      s[m][n] = *(const v4f*)&bmv[(u32)(((m*4 + n)*16 + lr)*16 + lg*4)];

  // Q.K^T on top of bias
  v8bf aq[4], bk4[4];
  #pragma unroll
  for (int m = 0; m < 4; ++m) aq[m]  = *(const v8bf*)(qb + (m*16 + lr)*32 + lg*8);
  #pragma unroll
  for (int n = 0; n < 4; ++n) bk4[n] = *(const v8bf*)(kb + (n*16 + lr)*32 + lg*8);
  #pragma unroll
  for (int m = 0; m < 4; ++m)
    #pragma unroll
    for (int n = 0; n < 4; ++n) s[m][n] = MFMA16(aq[m], bk4[n], s[m][n]);

  // P = exp(s), packed store (pos = lr*4+n), XOR-swizzled rows
  #pragma unroll
  for (int m = 0; m < 4; ++m)
    #pragma unroll
    for (int r = 0; r < 4; ++r){
      int row = m*16 + lg*4 + r;
      v4u16 pk;
      pk[0] = f2bf(__expf(s[m][0][r]));
      pk[1] = f2bf(__expf(s[m][1][r]));
      pk[2] = f2bf(__expf(s[m][2][r]));
      pk[3] = f2bf(__expf(s[m][3][r]));
      *(v4u16*)((char*)&plds[wv][0] + row*128 + ((lr*8) ^ ((row & 7) << 4))) = pk;
    }

  v8bf pa[4][2];
  #pragma unroll
  for (int m2 = 0; m2 < 4; ++m2)
    #pragma unroll
    for (int ksi = 0; ksi < 2; ++ksi){
      int row2 = m2*16 + lr;
      pa[m2][ksi] = *(const v8bf*)((const char*)&plds[wv][0] + row2*128 +
                                   ((ksi*64 + lg*16) ^ ((row2 & 7) << 4)));
    }

  // ones B-frag (col 0 only) for row-sums
  v8u16 onesu;
  #pragma unroll
  for (int e = 0; e < 8; ++e) onesu[e] = (lr == 0) ? (u16)0x3F80 : (u16)0;
  const v8bf onesf = __builtin_bit_cast(v8bf, onesu);

  const v4f zf = {0.f, 0.f, 0.f, 0.f};
  v4f o2[4][2], sacc[4];
  #pragma unroll
  for (int m2 = 0; m2 < 4; ++m2){
    o2[m2][0] = zf; o2[m2][1] = zf; sacc[m2] = zf;
  }
  #pragma unroll
  for (int ksi = 0; ksi < 2; ++ksi)
    #pragma unroll
    for (int m2 = 0; m2 < 4; ++m2){
      o2[m2][0] = MFMA16(pa[m2][ksi], __builtin_bit_cast(v8bf, bvu[0][ksi]), o2[m2][0]);
      o2[m2][1] = MFMA16(pa[m2][ksi], __builtin_bit_cast(v8bf, bvu[1][ksi]), o2[m2][1]);
      sacc[m2]  = MFMA16(pa[m2][ksi], onesf, sacc[m2]);
    }

  float inv[4][4];
  #pragma unroll
  for (int m2 = 0; m2 < 4; ++m2)
    #pragma unroll
    for (int r = 0; r < 4; ++r)
      inv[m2][r] = 1.0f / __shfl(sacc[m2][r], lnn & 48, 64);

  #pragma unroll
  for (int m2 = 0; m2 < 4; ++m2){
    #pragma unroll
    for (int n2 = 0; n2 < 2; ++n2){
      #pragma unroll
      for (int r = 0; r < 4; ++r){
        int row = m2*16 + lg*4 + r;
        if (row < 49){
          float val = o2[m2][n2][r] * inv[m2][r];
          aout[(w * 49u + (u32)row) * 192u + (u32)(h*32 + n2*16 + lr)] = f2bf(val);
        }
      }
    }
  }
}

// ------------------------------ launcher -----------------------------------
extern "C" void kernel_launch(void* const* d_in, const int* in_sizes, int n_in,
                              void* d_out, int out_size, void* d_ws, size_t ws_size,
                              hipStream_t stream){
  const float* x     = (const float*)d_in[0];
  const float* n1g   = (const float*)d_in[1];
  const float* n1b   = (const float*)d_in[2];
  const float* qkvw  = (const float*)d_in[3];
  const float* qkvb  = (const float*)d_in[4];
  const float* rpb   = (const float*)d_in[5];
  const float* projw = (const float*)d_in[6];
  const float* projb = (const float*)d_in[7];
  const float* n2g   = (const float*)d_in[8];
  const float* n2b   = (const float*)d_in[9];
  const float* fc1w  = (const float*)d_in[10];
  const float* fc1b  = (const float*)d_in[11];
  const float* fc2w  = (const float*)d_in[12];
  const float* fc2b  = (const float*)d_in[13];
  float* out = (float*)d_out;

  // ws layout (chunk buffers reused; everything < 122MB):
  char* ws   = (char*)d_ws;
  u16* bigC  = (u16*)ws;                      // qkvC 58MB / h1C 77MB
  u16* xwC   = (u16*)(ws + 80000000L);        // 19.3MB (xw / xln2 chunk)
  u16* aoC   = (u16*)(ws + 100000000L);       // 19.3MB (attn out chunk)
  float* bmt = (float*)(ws + 120000000L);     // 0.4MB
  u16* wq    = (u16*)(ws + 121000000L);       // 0.9MB weights
  u16* wp    = wq + 110592;
  u16* w1    = wp + 36864;
  u16* w2    = w1 + 147456;

  convw<<<1728, 256, 0, stream>>>(qkvw, projw, fc1w, fc2w, wq);
  bmt_k<<<384, 256, 0, stream>>>(rpb, bmt);

  // attention pipeline, L3-blocked: 8 chunks x 1024 windows (50176 rows)
  const u32 HC = 9633792u;                    // 1024*6*49*32
  for (int c = 0; c < 8; ++c){
    const int rowOff = c * 50176;
    // LN1 + shift + window partition -> xwC (chunk-local)
    ln_kern<true><<<3136, 256, 0, stream>>>(x, n1g, n1b, xwC, rowOff);
    // qkv -> qkvC
    gemm_bt<0, 192, 192><<<392*9, 512, 0, stream>>>(xwC, 0, wq, 192, 9,
                                                    qkvb, bigC, nullptr,
                                                    nullptr, 0, HC);
    // attention -> aoC
    attn_k<<<1536, 256, 0, stream>>>(bigC, bmt, aoC, (u32)(c * 1024), HC);
    // proj + scatter + residual -> d_out (global rows rowOff..)
    gemm_bt<1, 192, 192><<<392*3, 512, 0, stream>>>(aoC, 0, wp, 192, 3,
                                                    projb, nullptr, out,
                                                    x, rowOff, 0);
  }

  // MLP, L3-blocked: 8 chunks x 50176 tokens
  for (int c = 0; c < 8; ++c){
    const int off = c * 50176;
    // LN2 (linear) -> xwC (reused as xln2 chunk)
    ln_kern<false><<<3136, 256, 0, stream>>>(out, n2g, n2b, xwC, off);
    // fc1 + gelu -> h1C
    gemm_bt<2, 192, 192><<<392*12, 512, 0, stream>>>(xwC, 0, w1, 192, 12,
                                                     fc1b, bigC, nullptr,
                                                     nullptr, 0, 0);
    // fc2 += out (global rows off..)
    gemm_bt<3, 768, 768><<<392*3, 512, 0, stream>>>(bigC, 0, w2, 768, 3,
                                                    fc2b, nullptr, out,
                                                    nullptr, off, 0);
  }
}

// Round 19
// 1304.427 us; speedup vs baseline: 1.0535x; 1.0535x over previous
//
#include <hip/hip_runtime.h>
#include <stdint.h>
#include <math.h>

// ---------------------------------------------------------------------------
// Swin block, MI355X. B=32 H=W=112 C=192 NH=6 hd=32 WS=7 SS=3 -> 8192 windows,
// 49 tokens, 401408 token-rows.
// R19 = R16 verbatim (measured champion, 1303us). R17/R18 established that
// BOTH the merged chunk loop (~250MB working set vs 256MB L3) and the attn
// tweaks (5 blocks/CU bound + V-hoist) regress ~60-70us each; the R16
// configuration is the optimum of the explored design space:
//   - two separated L3-blocked chunk loops (8 x 1024 windows / 8 x 50176
//     tokens), chunk buffers reused in-place for L3 write elision;
//   - gemm_bt: 512-thr 8-wave, XCD-aligned group swizzle, per-EPI epilogue
//     orientation (qkv transposed/packed; proj/fc1/fc2 untransposed);
//   - attn: (256,4), bias+mask table C-init, no max-pass, ones-MFMA rowsums.
// ---------------------------------------------------------------------------

typedef unsigned short u16;
typedef unsigned int   u32;
typedef __bf16 v8bf __attribute__((ext_vector_type(8)));
typedef float  v4f  __attribute__((ext_vector_type(4)));
typedef u16    v8u16 __attribute__((ext_vector_type(8)));
typedef u16    v4u16 __attribute__((ext_vector_type(4)));

#define MFMA16(a,b,c) __builtin_amdgcn_mfma_f32_16x16x32_bf16(a,b,c,0,0,0)

#define QSC  0.17677669529663687f

__device__ __forceinline__ u16 f2bf(float f){
  return __builtin_bit_cast(u16, (__bf16)f);   // v_cvt RNE
}

__device__ __forceinline__ void async16(void* lds, const void* g){
  __builtin_amdgcn_global_load_lds(
      (__attribute__((address_space(1))) void*)(g),
      (__attribute__((address_space(3))) void*)(lds), 16, 0, 0);
}

// --------------------- combined weight convert (contiguous dst) ------------
// q-rows of qkv_w (first 192*192 elems) pre-scaled by hd^-0.5.
__global__ __launch_bounds__(256)
void convw(const float* __restrict__ s0, const float* __restrict__ s1,
           const float* __restrict__ s2, const float* __restrict__ s3,
           u16* __restrict__ d){
  int i = blockIdx.x * 256 + threadIdx.x;        // < 442368
  float v;
  if (i < 110592){
    v = s0[i];
    if (i < 36864) v *= QSC;
  }
  else if (i < 147456)  v = s1[i - 110592];
  else if (i < 294912)  v = s2[i - 147456];
  else                  v = s3[i - 294912];
  d[i] = f2bf(v);
}

// -------------------- fused rel-pos-bias + shift-mask table ----------------
// layout: [cls][h][m][n][lr][lg*4+r]  (matches MFMA C fragment, b128/lane)
__global__ __launch_bounds__(256)
void bmt_k(const float* __restrict__ rpb, float* __restrict__ bmt){
  int idx = blockIdx.x * 256 + threadIdx.x;      // 98304 total
  int r  = idx & 3, lg = (idx >> 2) & 3, lr = (idx >> 4) & 15;
  int n  = (idx >> 8) & 3, m = (idx >> 10) & 3;
  int t  = idx >> 12; int h = t % 6, cls = t / 6;
  int row = m*16 + lg*4 + r, col = n*16 + lr;
  float v;
  if (row >= 49 || col >= 49){
    v = -1e30f;
  } else {
    int i1 = row / 7, j1 = row - i1 * 7;
    int i2 = col / 7, j2 = col - i2 * 7;
    int ridx = (i1 - i2 + 6) * 13 + (j1 - j2 + 6);
    v = rpb[ridx * 6 + h];
    int lh1 = (cls & 2) ? (i1 < 4 ? 1 : 2) : 0;
    int lw1 = (cls & 1) ? (j1 < 4 ? 1 : 2) : 0;
    int lh2 = (cls & 2) ? (i2 < 4 ? 1 : 2) : 0;
    int lw2 = (cls & 1) ? (j2 < 4 ? 1 : 2) : 0;
    if (lh1 * 3 + lw1 != lh2 * 3 + lw2) v -= 100.f;
  }
  bmt[idx] = v;
}

// ----------------------- LayerNorm (optionally gathered, chunked) ----------
// 16 lanes per token, 4 tokens per wave; lane handles 12 channels (3 float4).
template<bool GATHER>
__global__ __launch_bounds__(256)
void ln_kern(const float* __restrict__ x, const float* __restrict__ g,
             const float* __restrict__ b, u16* __restrict__ o, int rowOff){
  const int ts  = threadIdx.x >> 4;
  const int l16 = threadIdx.x & 15;
  const int rl  = blockIdx.x * 16 + ts;          // chunk-local row
  const int r   = rowOff + rl;                   // global row
  const float* src;
  if (GATHER){
    u32 wdx = (u32)r / 49u; int nn = r - (int)wdx * 49;
    int bb = (int)(wdx >> 8); int wl = (int)(wdx & 255);
    int wh = wl >> 4, wwi = wl & 15;
    int ii = (int)((u32)nn / 7u), jj = nn - ii * 7;
    int th = wh * 7 + ii + 3;  if (th >= 112) th -= 112;
    int tw = wwi * 7 + jj + 3; if (tw >= 112) tw -= 112;
    src = x + (u32)(bb * 12544 + th * 112 + tw) * 192u;
  } else {
    src = x + (u32)r * 192u;
  }
  const float4 a0 = *(const float4*)(src + l16*12);
  const float4 a1 = *(const float4*)(src + l16*12 + 4);
  const float4 a2 = *(const float4*)(src + l16*12 + 8);
  float sm = ((a0.x+a0.y)+(a0.z+a0.w)) + ((a1.x+a1.y)+(a1.z+a1.w))
           + ((a2.x+a2.y)+(a2.z+a2.w));
  float sq = ((a0.x*a0.x+a0.y*a0.y)+(a0.z*a0.z+a0.w*a0.w))
           + ((a1.x*a1.x+a1.y*a1.y)+(a1.z*a1.z+a1.w*a1.w))
           + ((a2.x*a2.x+a2.y*a2.y)+(a2.z*a2.z+a2.w*a2.w));
  #pragma unroll
  for (int d = 1; d < 16; d <<= 1){
    sm += __shfl_xor(sm, d, 64);
    sq += __shfl_xor(sq, d, 64);
  }
  float mean = sm * (1.f/192.f);
  float var  = sq * (1.f/192.f) - mean * mean;
  float rs   = rsqrtf(var + 1e-5f);
  const float4 g0 = *(const float4*)(g + l16*12);
  const float4 g1 = *(const float4*)(g + l16*12 + 4);
  const float4 g2 = *(const float4*)(g + l16*12 + 8);
  const float4 b0 = *(const float4*)(b + l16*12);
  const float4 b1 = *(const float4*)(b + l16*12 + 4);
  const float4 b2 = *(const float4*)(b + l16*12 + 8);
  u16* dst = o + (u32)rl * 192u + l16 * 12;
  v4u16 w0, w1, w2;
  w0[0]=f2bf((a0.x-mean)*rs*g0.x+b0.x); w0[1]=f2bf((a0.y-mean)*rs*g0.y+b0.y);
  w0[2]=f2bf((a0.z-mean)*rs*g0.z+b0.z); w0[3]=f2bf((a0.w-mean)*rs*g0.w+b0.w);
  w1[0]=f2bf((a1.x-mean)*rs*g1.x+b1.x); w1[1]=f2bf((a1.y-mean)*rs*g1.y+b1.y);
  w1[2]=f2bf((a1.z-mean)*rs*g1.z+b1.z); w1[3]=f2bf((a1.w-mean)*rs*g1.w+b1.w);
  w2[0]=f2bf((a2.x-mean)*rs*g2.x+b2.x); w2[1]=f2bf((a2.y-mean)*rs*g2.y+b2.y);
  w2[2]=f2bf((a2.z-mean)*rs*g2.z+b2.z); w2[3]=f2bf((a2.w-mean)*rs*g2.w+b2.w);
  *(v4u16*)(dst)     = w0;
  *(v4u16*)(dst + 4) = w1;
  *(v4u16*)(dst + 8) = w2;
}

// ------------------------------- GEMM (A @ W^T) ----------------------------
// BM=128, BN=64, BK=192/stage, 512 threads = 8 waves, wave = 32x32 quadrant.
// 1D grid, XCD-aligned group swizzle (56 row-blocks x ncol, col-major).
// TRN = (EPI==0): acc[n][m] = mfma(wf, af) -> D[channel][token], packed 8B
// stores (chunk-local qkv, stride hstr). Else acc[m][n] -> D[token][channel].
// EPI: 0 qkv chunk store | 1 proj scatter+residual (global row = oRowOff+..)
//      2 fc1 gelu (chunk-local) | 3 fc2 linear += at global oRowOff
template<int EPI, int LDA, int LDW>
__global__ __launch_bounds__(512)
void gemm_bt(const u16* __restrict__ A, int aRowOff,
             const u16* __restrict__ W, int K, int ncol,
             const float* __restrict__ bias,
             u16* __restrict__ ob, float* __restrict__ of,
             const float* __restrict__ xres, int oRowOff, u32 hstr){
  constexpr bool TRN = (EPI == 0);
  __shared__ __align__(16) u16 sA[128 * 200];
  __shared__ __align__(16) u16 sW[64 * 200];
  const int tid = threadIdx.x;
  const int wv = tid >> 6, lnn = tid & 63;
  const int lr = lnn & 15, lg = lnn >> 4;
  // group swizzle
  const int win = 56 * ncol;
  const int grp = (int)blockIdx.x / win, loc = (int)blockIdx.x - grp * win;
  const int rloc = loc % 56, cblk = loc / 56;
  const int m0   = (grp * 56 + rloc) * 128;
  const int col0 = cblk * 64;
  const int wr = wv >> 1, wc = wv & 1;

  const int c0   = col0 + wc*32 + lr;        // untransposed: channel per lane
  const int chb0 = col0 + wc*32 + lg*4;      // transposed: 4-channel base
  const int chb1 = chb0 + 16;

  v4f acc[2][2];     // TRN: [n][m] channel-major; else [m][n] token-major
  if (TRN){
    float4 bv0 = *(const float4*)&bias[chb0];
    float4 bv1 = *(const float4*)&bias[chb1];
    if (chb0 < 192){ bv0.x*=QSC; bv0.y*=QSC; bv0.z*=QSC; bv0.w*=QSC; }
    if (chb1 < 192){ bv1.x*=QSC; bv1.y*=QSC; bv1.z*=QSC; bv1.w*=QSC; }
    acc[0][0] = acc[0][1] = (v4f){bv0.x, bv0.y, bv0.z, bv0.w};
    acc[1][0] = acc[1][1] = (v4f){bv1.x, bv1.y, bv1.z, bv1.w};
  } else {
    const float b0v = bias[c0];
    const float b1v = bias[c0 + 16];
    #pragma unroll
    for (int m = 0; m < 2; ++m){
      acc[m][0] = (v4f){b0v, b0v, b0v, b0v};
      acc[m][1] = (v4f){b1v, b1v, b1v, b1v};
    }
  }

  const int rA0 = (int)((u32)tid / 25u);
  const int cA0 = tid - rA0 * 25;
  const u32 aBase = (u32)(aRowOff + m0);
  const int nK = K / 192;
  for (int ks = 0; ks < nK; ++ks){
    if (ks) __syncthreads();
    const int k0 = ks * 192;
    // A tile: 128 rows x 25 chunks(16B) = 3200; 6 iters + 128-tail
    int ra = rA0, ca = cA0;
    #pragma unroll
    for (int it = 0; it < 6; ++it){
      int cc = (ca == 24) ? 23 : ca;
      async16((char*)sA + (size_t)(it * 512 + wv * 64) * 16,
              A + (aBase + (u32)ra) * (u32)LDA + (u32)(k0 + cc * 8));
      ra += 20; ca += 12; if (ca >= 25){ ca -= 25; ra += 1; }
    }
    if (tid < 128){
      int cc = (ca == 24) ? 23 : ca;
      async16((char*)sA + (size_t)(3072 + wv * 64) * 16,
              A + (aBase + (u32)ra) * (u32)LDA + (u32)(k0 + cc * 8));
    }
    // W tile: 64 rows x 25 chunks = 1600; 3 iters + 64-tail
    int rw = rA0, cw = cA0;
    #pragma unroll
    for (int it = 0; it < 3; ++it){
      int cc = (cw == 24) ? 23 : cw;
      async16((char*)sW + (size_t)(it * 512 + wv * 64) * 16,
              W + (u32)(col0 + rw) * (u32)LDW + (u32)(k0 + cc * 8));
      rw += 20; cw += 12; if (cw >= 25){ cw -= 25; rw += 1; }
    }
    if (tid < 64){
      int cc = (cw == 24) ? 23 : cw;
      async16((char*)sW + (size_t)1536 * 16,
              W + (u32)(col0 + rw) * (u32)LDW + (u32)(k0 + cc * 8));
    }
    __syncthreads();   // drains vmcnt(0) -> staged data visible

    #pragma unroll
    for (int kk = 0; kk < 6; ++kk){
      v8bf af[2], wf[2];
      #pragma unroll
      for (int m = 0; m < 2; ++m)
        af[m] = *(const v8bf*)&sA[(wr*32 + m*16 + lr) * 200 + kk*32 + lg*8];
      #pragma unroll
      for (int n = 0; n < 2; ++n)
        wf[n] = *(const v8bf*)&sW[(wc*32 + n*16 + lr) * 200 + kk*32 + lg*8];
      if (TRN){
        #pragma unroll
        for (int n = 0; n < 2; ++n)
          #pragma unroll
          for (int m = 0; m < 2; ++m)
            acc[n][m] = MFMA16(wf[n], af[m], acc[n][m]);
      } else {
        #pragma unroll
        for (int m = 0; m < 2; ++m)
          #pragma unroll
          for (int n = 0; n < 2; ++n)
            acc[m][n] = MFMA16(af[m], wf[n], acc[m][n]);
      }
    }
  }

  // ------------------------------ epilogues --------------------------------
  if (EPI == 0){
    // TRN: D row = channel (4*lg+r), D col = token (lr); packed 8B stores.
    u32 chpart[2];
    const int chbs[2] = {chb0, chb1};
    #pragma unroll
    for (int n = 0; n < 2; ++n){
      int ch = chbs[n];
      int which = (ch >= 384) ? 2 : ((ch >= 192) ? 1 : 0);
      int rem = ch - which * 192;
      chpart[n] = (u32)which * hstr + (u32)((rem >> 5) * 1568 + (rem & 31));
    }
    #pragma unroll
    for (int m = 0; m < 2; ++m){
      const int t = m0 + wr*32 + m*16 + lr;
      u32 wdx = (u32)t / 49u; u32 tnn = (u32)t - wdx * 49u;
      const u32 rowpart = wdx * 9408u + tnn * 32u;
      #pragma unroll
      for (int n = 0; n < 2; ++n){
        v4u16 pk;
        pk[0] = f2bf(acc[n][m][0]); pk[1] = f2bf(acc[n][m][1]);
        pk[2] = f2bf(acc[n][m][2]); pk[3] = f2bf(acc[n][m][3]);
        *(v4u16*)&ob[chpart[n] + rowpart] = pk;
      }
    }
  } else if (EPI == 1){
    // global row = oRowOff + local; window->spatial scatter + residual
    #pragma unroll
    for (int m = 0; m < 2; ++m){
      #pragma unroll
      for (int r = 0; r < 4; ++r){
        const int gr = oRowOff + m0 + wr*32 + m*16 + lg*4 + r;
        u32 wdx = (u32)gr / 49u; int nn = gr - (int)wdx * 49;
        int bb = (int)(wdx >> 8); int wl = (int)(wdx & 255);
        int wh = wl >> 4, wwi = wl & 15;
        int ii = (int)((u32)nn / 7u), jj = nn - ii * 7;
        int th = wh * 7 + ii + 3;  if (th >= 112) th -= 112;
        int tw = wwi * 7 + jj + 3; if (tw >= 112) tw -= 112;
        u32 adr = (u32)(bb * 12544 + th * 112 + tw) * 192u + (u32)c0;
        of[adr]      = xres[adr]      + acc[m][0][r];
        of[adr + 16] = xres[adr + 16] + acc[m][1][r];
      }
    }
  } else if (EPI == 3){
    // rows already spatial -> linear += at global oRowOff (lane-contiguous)
    #pragma unroll
    for (int m = 0; m < 2; ++m){
      #pragma unroll
      for (int r = 0; r < 4; ++r){
        const u32 adr = (u32)(oRowOff + m0 + wr*32 + m*16 + lg*4 + r) * 192u
                        + (u32)c0;
        of[adr]      += acc[m][0][r];
        of[adr + 16] += acc[m][1][r];
      }
    }
  } else {  // EPI == 2: gelu -> h1 chunk-local bf16, lane-contiguous
    #pragma unroll
    for (int m = 0; m < 2; ++m){
      #pragma unroll
      for (int r = 0; r < 4; ++r){
        const u32 base = (u32)(m0 + wr*32 + m*16 + lg*4 + r) * 768u + (u32)c0;
        float v0 = acc[m][0][r], v1 = acc[m][1][r];
        ob[base]      = f2bf(0.5f * v0 * (1.0f + erff(v0 * 0.7071067811865475f)));
        ob[base + 16] = f2bf(0.5f * v1 * (1.0f + erff(v1 * 0.7071067811865475f)));
      }
    }
  }
}

// ------------------------------- attention (chunk-local I/O) ---------------
// one wave per (window, head); 4 waves / block.  49 padded to 64.
// gid chunk-local; wOff (mult of 256) used only for the mask class; aout is
// the chunk-local buffer (written at local window index).
__global__ __launch_bounds__(256, 4)
void attn_k(const u16* __restrict__ qkv, const float* __restrict__ bmt,
            u16* __restrict__ aout, u32 wOff, u32 hstr){
  __shared__ __align__(16) u16 plds[4][64 * 64];   // 32 KB total
  const int wv = threadIdx.x >> 6, lnn = threadIdx.x & 63;
  const int lr = lnn & 15, lg = lnn >> 4;
  const u32 gid = (u32)blockIdx.x * 4u + (u32)wv;   // chunk-local
  const u32 w = gid / 6u; const int h = (int)(gid - w * 6u);
  const u16* qb = qkv + (size_t)gid * 1568;
  const u16* kb = qb + hstr;
  const u16* vb = kb + hstr;
  const u32 wg = w + wOff;                          // global window (mask only)

  // C-init = bias+mask table (b128 per lane, L2/L3-resident)
  const int wl = (int)(wg & 255u);
  const int cls = (((wl >> 4) == 15) ? 2 : 0) | (((wl & 15) == 15) ? 1 : 0);
  const float* bmv = bmt + ((u32)(cls * 6 + h) << 12);
  v4f s[4][4];
  #pragma unroll
  for (int m = 0; m < 4; ++m)
    #pragma unroll
    for (int n = 0; n < 4; ++n)
      s[m][n] = *(const v4f*)&bmv[(u32)(((m*4 + n)*16 + lr)*16 + lg*4)];

  // Q.K^T on top of bias
  v8bf aq[4], bk4[4];
  #pragma unroll
  for (int m = 0; m < 4; ++m) aq[m]  = *(const v8bf*)(qb + (m*16 + lr)*32 + lg*8);
  #pragma unroll
  for (int n = 0; n < 4; ++n) bk4[n] = *(const v8bf*)(kb + (n*16 + lr)*32 + lg*8);
  #pragma unroll
  for (int m = 0; m < 4; ++m)
    #pragma unroll
    for (int n = 0; n < 4; ++n) s[m][n] = MFMA16(aq[m], bk4[n], s[m][n]);

  // V fragments from global, k-permuted (pads multiply P==0 -> harmless)
  v8u16 bvu[2][2];
  #pragma unroll
  for (int n2 = 0; n2 < 2; ++n2)
    #pragma unroll
    for (int ksi = 0; ksi < 2; ++ksi)
      #pragma unroll
      for (int e = 0; e < 8; ++e){
        int kp = ksi * 32 + lg * 8 + e;
        int t  = (kp >> 2) + (kp & 3) * 16;
        bvu[n2][ksi][e] = vb[(u32)(t * 32 + n2 * 16 + lr)];
      }

  // P = exp(s), packed store (pos = lr*4+n), XOR-swizzled rows
  #pragma unroll
  for (int m = 0; m < 4; ++m)
    #pragma unroll
    for (int r = 0; r < 4; ++r){
      int row = m*16 + lg*4 + r;
      v4u16 pk;
      pk[0] = f2bf(__expf(s[m][0][r]));
      pk[1] = f2bf(__expf(s[m][1][r]));
      pk[2] = f2bf(__expf(s[m][2][r]));
      pk[3] = f2bf(__expf(s[m][3][r]));
      *(v4u16*)((char*)&plds[wv][0] + row*128 + ((lr*8) ^ ((row & 7) << 4))) = pk;
    }

  v8bf pa[4][2];
  #pragma unroll
  for (int m2 = 0; m2 < 4; ++m2)
    #pragma unroll
    for (int ksi = 0; ksi < 2; ++ksi){
      int row2 = m2*16 + lr;
      pa[m2][ksi] = *(const v8bf*)((const char*)&plds[wv][0] + row2*128 +
                                   ((ksi*64 + lg*16) ^ ((row2 & 7) << 4)));
    }

  // ones B-frag (col 0 only) for row-sums
  v8u16 onesu;
  #pragma unroll
  for (int e = 0; e < 8; ++e) onesu[e] = (lr == 0) ? (u16)0x3F80 : (u16)0;
  const v8bf onesf = __builtin_bit_cast(v8bf, onesu);

  const v4f zf = {0.f, 0.f, 0.f, 0.f};
  v4f o2[4][2], sacc[4];
  #pragma unroll
  for (int m2 = 0; m2 < 4; ++m2){
    o2[m2][0] = zf; o2[m2][1] = zf; sacc[m2] = zf;
  }
  #pragma unroll
  for (int ksi = 0; ksi < 2; ++ksi)
    #pragma unroll
    for (int m2 = 0; m2 < 4; ++m2){
      o2[m2][0] = MFMA16(pa[m2][ksi], __builtin_bit_cast(v8bf, bvu[0][ksi]), o2[m2][0]);
      o2[m2][1] = MFMA16(pa[m2][ksi], __builtin_bit_cast(v8bf, bvu[1][ksi]), o2[m2][1]);
      sacc[m2]  = MFMA16(pa[m2][ksi], onesf, sacc[m2]);
    }

  float inv[4][4];
  #pragma unroll
  for (int m2 = 0; m2 < 4; ++m2)
    #pragma unroll
    for (int r = 0; r < 4; ++r)
      inv[m2][r] = 1.0f / __shfl(sacc[m2][r], lnn & 48, 64);

  #pragma unroll
  for (int m2 = 0; m2 < 4; ++m2){
    #pragma unroll
    for (int n2 = 0; n2 < 2; ++n2){
      #pragma unroll
      for (int r = 0; r < 4; ++r){
        int row = m2*16 + lg*4 + r;
        if (row < 49){
          float val = o2[m2][n2][r] * inv[m2][r];
          aout[(w * 49u + (u32)row) * 192u + (u32)(h*32 + n2*16 + lr)] = f2bf(val);
        }
      }
    }
  }
}

// ------------------------------ launcher -----------------------------------
extern "C" void kernel_launch(void* const* d_in, const int* in_sizes, int n_in,
                              void* d_out, int out_size, void* d_ws, size_t ws_size,
                              hipStream_t stream){
  const float* x     = (const float*)d_in[0];
  const float* n1g   = (const float*)d_in[1];
  const float* n1b   = (const float*)d_in[2];
  const float* qkvw  = (const float*)d_in[3];
  const float* qkvb  = (const float*)d_in[4];
  const float* rpb   = (const float*)d_in[5];
  const float* projw = (const float*)d_in[6];
  const float* projb = (const float*)d_in[7];
  const float* n2g   = (const float*)d_in[8];
  const float* n2b   = (const float*)d_in[9];
  const float* fc1w  = (const float*)d_in[10];
  const float* fc1b  = (const float*)d_in[11];
  const float* fc2w  = (const float*)d_in[12];
  const float* fc2b  = (const float*)d_in[13];
  float* out = (float*)d_out;

  // ws layout (all chunk buffers reused; everything < 122MB):
  char* ws   = (char*)d_ws;
  u16* bigC  = (u16*)ws;                      // qkvC 58MB / h1C 77MB
  u16* xwC   = (u16*)(ws + 80000000L);        // 19.3MB (xw / xln2 chunk)
  u16* aoC   = (u16*)(ws + 100000000L);       // 19.3MB (attn out chunk)
  float* bmt = (float*)(ws + 120000000L);     // 0.4MB
  u16* wq    = (u16*)(ws + 121000000L);       // 0.9MB weights
  u16* wp    = wq + 110592;
  u16* w1    = wp + 36864;
  u16* w2    = w1 + 147456;

  convw<<<1728, 256, 0, stream>>>(qkvw, projw, fc1w, fc2w, wq);
  bmt_k<<<384, 256, 0, stream>>>(rpb, bmt);

  // attention pipeline, L3-blocked: 8 chunks x 1024 windows (50176 rows)
  const u32 HC = 9633792u;                    // 1024*6*49*32
  for (int c = 0; c < 8; ++c){
    const int rowOff = c * 50176;
    // LN1 + shift + window partition -> xwC (chunk-local)
    ln_kern<true><<<3136, 256, 0, stream>>>(x, n1g, n1b, xwC, rowOff);
    // qkv -> qkvC
    gemm_bt<0, 192, 192><<<392*9, 512, 0, stream>>>(xwC, 0, wq, 192, 9,
                                                    qkvb, bigC, nullptr,
                                                    nullptr, 0, HC);
    // attention -> aoC
    attn_k<<<1536, 256, 0, stream>>>(bigC, bmt, aoC, (u32)(c * 1024), HC);
    // proj + scatter + residual -> d_out (global rows rowOff..)
    gemm_bt<1, 192, 192><<<392*3, 512, 0, stream>>>(aoC, 0, wp, 192, 3,
                                                    projb, nullptr, out,
                                                    x, rowOff, 0);
  }

  // MLP, L3-blocked: 8 chunks x 50176 tokens
  for (int c = 0; c < 8; ++c){
    const int off = c * 50176;
    // LN2 (linear) -> xwC (reused as xln2 chunk)
    ln_kern<false><<<3136, 256, 0, stream>>>(out, n2g, n2b, xwC, off);
    // fc1 + gelu -> h1C
    gemm_bt<2, 192, 192><<<392*12, 512, 0, stream>>>(xwC, 0, w1, 192, 12,
                                                     fc1b, bigC, nullptr,
                                                     nullptr, 0, 0);
    // fc2 += out (global rows off..)
    gemm_bt<3, 768, 768><<<392*3, 512, 0, stream>>>(bigC, 0, w2, 768, 3,
                                                    fc2b, nullptr, out,
                                                    nullptr, off, 0);
  }
}